// Round 7
// baseline (289.071 us; speedup 1.0000x reference)
//
#include <hip/hip_runtime.h>
#include <hip/hip_bf16.h>
#include <stdint.h>

#define IN_CH 794
#define KPAD  832            // 26 * 32 = 13 * 64
#define Z1C   1024
#define OUT_C 512
#define BATCH 32768

typedef __attribute__((ext_vector_type(8))) short short8;
typedef __attribute__((ext_vector_type(4))) float f32x4;

__device__ __forceinline__ ushort f2bf(float f) {
  uint32_t u = __float_as_uint(f);
  return (ushort)((u + 0x7fffu + ((u >> 16) & 1u)) >> 16);  // RTNE
}

__device__ __forceinline__ void glds16(const void* g, void* l) {
  __builtin_amdgcn_global_load_lds(
      (const __attribute__((address_space(1))) void*)g,
      (__attribute__((address_space(3))) void*)l, 16, 0, 0);
}

#define MFMA(a, b, c) __builtin_amdgcn_mfma_f32_16x16x32_bf16(a, b, c, 0, 0, 0)

// ---------------- prep: masked weights (bf16) + folded bias ----------------
__global__ __launch_bounds__(256) void prep1(
    const float* __restrict__ W1, const float* __restrict__ b1,
    const float* __restrict__ Wc1, const float* __restrict__ bc1,
    const float* __restrict__ MW0, ushort* __restrict__ w1p,
    float* __restrict__ bias1) {
  int z = blockIdx.x, t = threadIdx.x;
  float sum = 0.f;
  for (int i = t; i < KPAD; i += 256) {
    float w = 0.f;
    if (i < IN_CH) {
      float m = MW0[z * IN_CH + i];
      w = W1[z * IN_CH + i] * m;
      sum += Wc1[z * IN_CH + i] * m;
    }
    w1p[z * KPAD + i] = f2bf(w);
  }
#pragma unroll
  for (int o = 32; o > 0; o >>= 1) sum += __shfl_down(sum, o, 64);
  __shared__ float red[4];
  if ((t & 63) == 0) red[t >> 6] = sum;
  __syncthreads();
  if (t == 0) bias1[z] = b1[z] + bc1[z] + red[0] + red[1] + red[2] + red[3];
}

__global__ __launch_bounds__(256) void prep2(
    const float* __restrict__ W2, const float* __restrict__ b2,
    const float* __restrict__ Wc2, const float* __restrict__ bc2,
    const float* __restrict__ MW1, ushort* __restrict__ w2m,
    float* __restrict__ bias2) {
  int z = blockIdx.x, t = threadIdx.x;
  float sum = 0.f;
  for (int i = t; i < Z1C; i += 256) {
    float m = MW1[z * Z1C + i];
    w2m[z * Z1C + i] = f2bf(W2[z * Z1C + i] * m);
    sum += Wc2[z * Z1C + i] * m;
  }
#pragma unroll
  for (int o = 32; o > 0; o >>= 1) sum += __shfl_down(sum, o, 64);
  __shared__ float red[4];
  if ((t & 63) == 0) red[t >> 6] = sum;
  __syncthreads();
  if (t == 0) bias2[z] = b2[z] + bc2[z] + red[0] + red[1] + red[2] + red[3];
}

// =================== fused MADE: out = relu(relu(x@W1'^T+b1')@W2'^T+b2') ===================
// 256 blocks (1/CU), 512 thr (8 waves 2Mx4N). Block owns 128 batch rows.
// Per chunk c (4 chunks of 256 h1-cols):
//   stage1: 13 K-tiles (BK=64): A1 = x converted in-reg (T14 split) -> LDS,
//           B1 = w1p rows [c*256,+256) via pre-swizzled global_load_lds.
//           acc1[4][4] per wave (wave 64x64).
//   handoff: acc1 -> bias/relu/bf16 -> h1c LDS (64 KB, XOR-swizzled).
//   stage2: 4 K2-tiles x 2 passes (out cols p*256), acc2[2][4][4] persistent.
// LDS: A1 2x16KB | B shared 2x32KB (B1 db / B2 halves) | h1c 64KB = 160 KiB.
__global__ __launch_bounds__(512, 2) void fused(
    const float* __restrict__ x, const ushort* __restrict__ w1p,
    const ushort* __restrict__ w2m, const float* __restrict__ bias1,
    const float* __restrict__ bias2, float* __restrict__ out) {
  __shared__ uint4 ldsq[10240];        // 163840 B
  char* const LA = (char*)ldsq;        // A1: 2 x 16384
  char* const LB = LA + 32768;         // B:  2 x 32768
  char* const LH = LA + 98304;         // h1c: 65536
  const int tid = threadIdx.x;
  const int lane = tid & 63, wid = tid >> 6;
  const int wr = wid >> 2, wc = wid & 3;   // 2M x 4N
  const int brow = blockIdx.x * 128;

  // staging source (pre-swizzled global, involution with swizzled ds_read)
  const int srow = tid >> 3;                     // 0..63
  const int scol = ((tid & 7) * 16) ^ ((srow & 7) << 4);
  const int ldst = wid * 1024;
  const char* const w1b = (const char*)w1p + (size_t)srow * (KPAD * 2) + scol;
  const char* const w2b = (const char*)w2m + (size_t)srow * (Z1C * 2) + scol;

  // fragment-read ids
  const int rA = lane & 15;
  const int klo = (lane >> 4) * 16;
  const int xs = (rA & 7) << 4;

  // A1 conversion staging: thread -> (row, 16-elem k segment)
  const int arow = tid >> 2;                     // 0..127
  const int akseg = (tid & 3) * 16;              // 0/16/32/48
  const float* const xrow = x + (size_t)(brow + arow) * IN_CH;
  const int aswz = (arow & 7) << 4;
  const int awb = arow * 128 + ((akseg * 2) ^ aswz);
  const int awb2 = arow * 128 + ((akseg * 2 + 16) ^ aswz);

  float2 xv[8];
  auto ldA1 = [&](int kt) {  // issue x loads for tile kt (T14: issue early)
    const int k0 = kt * 64 + akseg;
    if (k0 + 16 <= IN_CH) {
#pragma unroll
      for (int j = 0; j < 8; ++j) xv[j] = *(const float2*)(xrow + k0 + 2 * j);
    } else {
#pragma unroll
      for (int j = 0; j < 8; ++j) {
        int c0 = k0 + 2 * j;
        float a = (c0 < IN_CH) ? xrow[c0] : 0.f;
        float b = (c0 + 1 < IN_CH) ? xrow[c0 + 1] : 0.f;
        xv[j] = make_float2(a, b);
      }
    }
  };
  auto wrA1 = [&](char* dst) {  // convert + ds_write (after MFMAs)
    union { ushort u[16]; uint4 q[2]; } pk;
#pragma unroll
    for (int j = 0; j < 8; ++j) {
      pk.u[2 * j] = f2bf(xv[j].x);
      pk.u[2 * j + 1] = f2bf(xv[j].y);
    }
    *(uint4*)(dst + awb) = pk.q[0];
    *(uint4*)(dst + awb2) = pk.q[1];
  };

  f32x4 acc2[2][4][4] = {};

#pragma unroll 1
  for (int c = 0; c < 4; ++c) {
    // ---------------- stage 1 ----------------
    f32x4 acc1[4][4] = {};
    {
#pragma unroll
      for (int h = 0; h < 4; ++h)
        glds16(w1b + (size_t)(c * 256 + h * 64) * (KPAD * 2),
               LB + h * 8192 + ldst);
      ldA1(0);
      wrA1(LA);
    }
    __syncthreads();

#pragma unroll 1
    for (int kt = 0; kt < 13; ++kt) {
      const int cur = kt & 1, nxt = cur ^ 1;
      if (kt < 12) {
#pragma unroll
        for (int h = 0; h < 4; ++h)
          glds16(w1b + (size_t)(c * 256 + h * 64) * (KPAD * 2) + (kt + 1) * 128,
                 LB + nxt * 32768 + h * 8192 + ldst);
        ldA1(kt + 1);
      }
      const char* Ab = LA + cur * 16384;
      const char* Bb = LB + cur * 32768;
      short8 af[4][2], bg[4][2];
#pragma unroll
      for (int m = 0; m < 4; ++m) {
        const int row = wr * 64 + m * 16 + rA;
        af[m][0] = *(const short8*)(Ab + row * 128 + (klo ^ xs));
        af[m][1] = *(const short8*)(Ab + row * 128 + ((64 + klo) ^ xs));
      }
#pragma unroll
      for (int n = 0; n < 4; ++n) {
        const int row = wc * 64 + n * 16 + rA;
        bg[n][0] = *(const short8*)(Bb + row * 128 + (klo ^ xs));
        bg[n][1] = *(const short8*)(Bb + row * 128 + ((64 + klo) ^ xs));
      }
      __builtin_amdgcn_s_setprio(1);
#pragma unroll
      for (int ks = 0; ks < 2; ++ks)
#pragma unroll
        for (int m = 0; m < 4; ++m)
#pragma unroll
          for (int n = 0; n < 4; ++n)
            acc1[m][n] = MFMA(af[m][ks], bg[n][ks], acc1[m][n]);
      __builtin_amdgcn_s_setprio(0);
      if (kt < 12) wrA1(LA + nxt * 16384);
      __syncthreads();
    }

    // ---------------- handoff: acc1 -> h1c (bias + relu + bf16) ----------------
#pragma unroll
    for (int n = 0; n < 4; ++n) {
      const float bv = bias1[c * 256 + wc * 64 + n * 16 + rA];
      const int C2 = (wc * 64 + n * 16 + rA) * 2;
#pragma unroll
      for (int m = 0; m < 4; ++m)
#pragma unroll
        for (int r = 0; r < 4; ++r) {
          const int R = wr * 64 + m * 16 + (lane >> 4) * 4 + r;
          float v = acc1[m][n][r] + bv;
          v = v > 0.f ? v : 0.f;
          *(ushort*)(LH + ((R * 512 + C2) ^ ((R & 7) << 4))) = f2bf(v);
        }
    }
    __syncthreads();

    // ---------------- stage 2: acc2 += h1c @ w2m_cslice^T ----------------
#pragma unroll 1
    for (int k2 = 0; k2 < 4; ++k2) {
#pragma unroll
      for (int h = 0; h < 4; ++h)
        glds16(w2b + (size_t)(h * 64) * (Z1C * 2) + c * 512 + k2 * 128,
               LB + h * 8192 + ldst);
#pragma unroll
      for (int h = 0; h < 4; ++h)
        glds16(w2b + (size_t)(256 + h * 64) * (Z1C * 2) + c * 512 + k2 * 128,
               LB + 32768 + h * 8192 + ldst);
      __syncthreads();
      short8 af[4][2];
#pragma unroll
      for (int m = 0; m < 4; ++m) {
        const int row = wr * 64 + m * 16 + rA;
        af[m][0] = *(const short8*)(LH + row * 512 + ((k2 * 128 + klo) ^ xs));
        af[m][1] =
            *(const short8*)(LH + row * 512 + ((k2 * 128 + 64 + klo) ^ xs));
      }
      __builtin_amdgcn_s_setprio(1);
#pragma unroll
      for (int p = 0; p < 2; ++p) {
        const char* Bb = LB + p * 32768;
        short8 bg[4][2];
#pragma unroll
        for (int n = 0; n < 4; ++n) {
          const int row = wc * 64 + n * 16 + rA;
          bg[n][0] = *(const short8*)(Bb + row * 128 + (klo ^ xs));
          bg[n][1] = *(const short8*)(Bb + row * 128 + ((64 + klo) ^ xs));
        }
#pragma unroll
        for (int ks = 0; ks < 2; ++ks)
#pragma unroll
          for (int m = 0; m < 4; ++m)
#pragma unroll
            for (int n = 0; n < 4; ++n)
              acc2[p][m][n] = MFMA(af[m][ks], bg[n][ks], acc2[p][m][n]);
      }
      __builtin_amdgcn_s_setprio(0);
      __syncthreads();
    }
  }

  // ---------------- out epilogue ----------------
#pragma unroll
  for (int p = 0; p < 2; ++p)
#pragma unroll
    for (int n = 0; n < 4; ++n) {
      const int col = p * 256 + wc * 64 + n * 16 + rA;
      const float bv = bias2[col];
#pragma unroll
      for (int m = 0; m < 4; ++m)
#pragma unroll
        for (int r = 0; r < 4; ++r) {
          const int row = brow + wr * 64 + m * 16 + (lane >> 4) * 4 + r;
          float v = acc2[p][m][n][r] + bv;
          out[(size_t)row * OUT_C + col] = v > 0.f ? v : 0.f;
        }
    }
}

extern "C" void kernel_launch(void* const* d_in, const int* in_sizes, int n_in,
                              void* d_out, int out_size, void* d_ws, size_t ws_size,
                              hipStream_t stream) {
  (void)in_sizes; (void)n_in; (void)out_size; (void)ws_size;
  const float* x   = (const float*)d_in[0];
  const float* W1  = (const float*)d_in[1];
  const float* b1  = (const float*)d_in[2];
  const float* Wc1 = (const float*)d_in[3];
  const float* bc1 = (const float*)d_in[4];
  const float* W2  = (const float*)d_in[5];
  const float* b2  = (const float*)d_in[6];
  const float* Wc2 = (const float*)d_in[7];
  const float* bc2 = (const float*)d_in[8];
  const float* MW0 = (const float*)d_in[9];
  const float* MW1 = (const float*)d_in[10];

  char* ws = (char*)d_ws;
  ushort* w1p   = (ushort*)ws;                   // 1024*832*2 = 1,703,936
  ushort* w2m   = (ushort*)(ws + 1703936);       //  512*1024*2 = 1,048,576
  float*  bias1 = (float*)(ws + 2752512);        // 4096
  float*  bias2 = (float*)(ws + 2756608);        // 2048

  float* out = (float*)d_out;

  prep1<<<1024, 256, 0, stream>>>(W1, b1, Wc1, bc1, MW0, w1p, bias1);
  prep2<<<512, 256, 0, stream>>>(W2, b2, Wc2, bc2, MW1, w2m, bias2);
  fused<<<256, 512, 0, stream>>>(x, w1p, w2m, bias1, bias2, out);
}

// Round 8
// 201.557 us; speedup vs baseline: 1.4342x; 1.4342x over previous
//
#include <hip/hip_runtime.h>
#include <hip/hip_bf16.h>
#include <stdint.h>

#define IN_CH 794
#define KPAD  832            // 26 * 32 = 13 * 64
#define Z1C   1024
#define OUT_C 512
#define BATCH 32768

typedef __attribute__((ext_vector_type(8))) short short8;
typedef __attribute__((ext_vector_type(4))) float f32x4;

__device__ __forceinline__ ushort f2bf(float f) {
  uint32_t u = __float_as_uint(f);
  return (ushort)((u + 0x7fffu + ((u >> 16) & 1u)) >> 16);  // RTNE
}

__device__ __forceinline__ void glds16(const void* g, void* l) {
  __builtin_amdgcn_global_load_lds(
      (const __attribute__((address_space(1))) void*)g,
      (__attribute__((address_space(3))) void*)l, 16, 0, 0);
}

#define MFMA(a, b, c) __builtin_amdgcn_mfma_f32_16x16x32_bf16(a, b, c, 0, 0, 0)

// ---------------- prep: masked weights (bf16) + folded bias ----------------
__global__ __launch_bounds__(256) void prep1(
    const float* __restrict__ W1, const float* __restrict__ b1,
    const float* __restrict__ Wc1, const float* __restrict__ bc1,
    const float* __restrict__ MW0, ushort* __restrict__ w1p,
    float* __restrict__ bias1) {
  int z = blockIdx.x, t = threadIdx.x;
  float sum = 0.f;
  for (int i = t; i < KPAD; i += 256) {
    float w = 0.f;
    if (i < IN_CH) {
      float m = MW0[z * IN_CH + i];
      w = W1[z * IN_CH + i] * m;
      sum += Wc1[z * IN_CH + i] * m;
    }
    w1p[z * KPAD + i] = f2bf(w);
  }
#pragma unroll
  for (int o = 32; o > 0; o >>= 1) sum += __shfl_down(sum, o, 64);
  __shared__ float red[4];
  if ((t & 63) == 0) red[t >> 6] = sum;
  __syncthreads();
  if (t == 0) bias1[z] = b1[z] + bc1[z] + red[0] + red[1] + red[2] + red[3];
}

__global__ __launch_bounds__(256) void prep2(
    const float* __restrict__ W2, const float* __restrict__ b2,
    const float* __restrict__ Wc2, const float* __restrict__ bc2,
    const float* __restrict__ MW1, ushort* __restrict__ w2m,
    float* __restrict__ bias2) {
  int z = blockIdx.x, t = threadIdx.x;
  float sum = 0.f;
  for (int i = t; i < Z1C; i += 256) {
    float m = MW1[z * Z1C + i];
    w2m[z * Z1C + i] = f2bf(W2[z * Z1C + i] * m);
    sum += Wc2[z * Z1C + i] * m;
  }
#pragma unroll
  for (int o = 32; o > 0; o >>= 1) sum += __shfl_down(sum, o, 64);
  __shared__ float red[4];
  if ((t & 63) == 0) red[t >> 6] = sum;
  __syncthreads();
  if (t == 0) bias2[z] = b2[z] + bc2[z] + red[0] + red[1] + red[2] + red[3];
}

// =================== fused MADE v2 (register-safe) ===================
// 256 blocks (1/CU), 512 thr (8 waves). Block owns 128 batch rows.
// 4 chunks of 256 h1-cols. Chunk 0: stage1 converts x in-reg (acc2 NOT yet
// live) and caches bf16 panel to xb (ws); chunks 1-3 re-stage A via glds16.
// Stage2: A from h1c LDS, B (w2m) straight from global (L2-resident) -> no
// B2 LDS, no stage2 barriers. LDS: A db 32K | B1 db 64K | h1c 64K = 160 KiB.
// Reg ledger worst (c>=1 stage1): acc2 128 + acc1 64 + af 32 + bg 8 + addr.
__global__ __launch_bounds__(512, 2) void fused(
    const float* __restrict__ x, const ushort* __restrict__ w1p,
    const ushort* __restrict__ w2m, const float* __restrict__ bias1,
    const float* __restrict__ bias2, ushort* __restrict__ xb,
    float* __restrict__ out) {
  __shared__ uint4 ldsq[10240];        // 163840 B
  char* const LA  = (char*)ldsq;       // A1 db: 2 x 16384
  char* const LB1 = LA + 32768;        // B1 db: 2 x 32768
  char* const LH  = LA + 98304;        // h1c:   65536
  const int tid = threadIdx.x, lane = tid & 63, wid = tid >> 6;
  const int wr = wid >> 2, wc = wid & 3;      // 2M x 4N
  const int brow = blockIdx.x * 128;

  const int rA = lane & 15;
  const int klo = (lane >> 4) * 16;
  const int xs = (rA & 7) << 4;
  // glds16 staging ids (64-col tiles, pre-swizzled source = rule #21)
  const int sr = tid >> 3;                                // 0..63
  const int sx = ((tid & 7) * 16) ^ ((sr & 7) << 4);
  const int ldst = wid * 1024;
  // convert ids (chunk 0): thread -> (row 0..127, 16-elem k segment)
  const int crow = tid >> 2;
  const int cseg = (tid & 3) * 16;
  const int csw = (crow & 7) << 4;
  const int cb0 = crow * 128 + ((cseg * 2) ^ csw);
  const int cb1 = crow * 128 + ((cseg * 2 + 16) ^ csw);
  const float* const xrow = x + (size_t)(brow + crow) * IN_CH;
  ushort* const xbrow = xb + (size_t)(brow + crow) * KPAD;

  f32x4 acc2[4][8];   // first written in chunk-0 stage2 (not live in stage1-0)

  float2 xv[8];
  auto ldx = [&](int kt) {
    const int k0 = kt * 64 + cseg;
    if (k0 + 16 <= IN_CH) {
#pragma unroll
      for (int j = 0; j < 8; ++j) xv[j] = *(const float2*)(xrow + k0 + 2 * j);
    } else {
#pragma unroll
      for (int j = 0; j < 8; ++j) {
        int e = k0 + 2 * j;
        xv[j].x = (e < IN_CH) ? xrow[e] : 0.f;
        xv[j].y = (e + 1 < IN_CH) ? xrow[e + 1] : 0.f;
      }
    }
  };
  auto cvt = [&](char* Abuf, int kt) {  // convert + LDS write + xb cache
    union { ushort u[16]; uint4 q[2]; } pk;
#pragma unroll
    for (int j = 0; j < 8; ++j) {
      pk.u[2 * j] = f2bf(xv[j].x);
      pk.u[2 * j + 1] = f2bf(xv[j].y);
    }
    *(uint4*)(Abuf + cb0) = pk.q[0];
    *(uint4*)(Abuf + cb1) = pk.q[1];
    *(uint4*)(xbrow + kt * 64 + cseg) = pk.q[0];
    *(uint4*)(xbrow + kt * 64 + cseg + 8) = pk.q[1];
  };
  auto stgB1 = [&](int c, int kt, int buf) {  // 256x64 tile, 4 glds
#pragma unroll
    for (int h = 0; h < 4; ++h) {
      int r = sr + h * 64;
      glds16((const char*)w1p + (size_t)(c * 256 + r) * 1664 +
                 (size_t)kt * 128 + sx,
             LB1 + buf * 32768 + h * 8192 + ldst);
    }
  };
  auto stgA = [&](int kt, int buf) {  // 128x64 tile from xb, 2 glds
#pragma unroll
    for (int h = 0; h < 2; ++h) {
      int r = sr + h * 64;
      glds16((const char*)xb + (size_t)(brow + r) * 1664 +
                 (size_t)kt * 128 + sx,
             LA + buf * 16384 + h * 8192 + ldst);
    }
  };
  auto s1body = [&](f32x4(&acc1)[4][4], int cur) {
    const char* Ab = LA + cur * 16384;
    const char* Bb = LB1 + cur * 32768;
    short8 af[4][2];
#pragma unroll
    for (int m = 0; m < 4; ++m) {
      int row = wr * 64 + m * 16 + rA;
      af[m][0] = *(const short8*)(Ab + row * 128 + (klo ^ xs));
      af[m][1] = *(const short8*)(Ab + row * 128 + ((64 + klo) ^ xs));
    }
#pragma unroll
    for (int n = 0; n < 4; ++n) {   // single-n clusters: bg liveness = 8
      short8 bg[2];
      int row = wc * 64 + n * 16 + rA;
      bg[0] = *(const short8*)(Bb + row * 128 + (klo ^ xs));
      bg[1] = *(const short8*)(Bb + row * 128 + ((64 + klo) ^ xs));
      __builtin_amdgcn_s_setprio(1);
#pragma unroll
      for (int ks = 0; ks < 2; ++ks)
#pragma unroll
        for (int m = 0; m < 4; ++m)
          acc1[m][n] = MFMA(af[m][ks], bg[ks], acc1[m][n]);
      __builtin_amdgcn_s_setprio(0);
    }
  };
  auto handoff = [&](f32x4(&acc1)[4][4], int c) {
#pragma unroll
    for (int n = 0; n < 4; ++n) {
      int col = wc * 64 + n * 16 + rA;
      float bv = bias1[c * 256 + col];
      int C2 = col * 2;
#pragma unroll
      for (int m = 0; m < 4; ++m)
#pragma unroll
        for (int r = 0; r < 4; ++r) {
          int R = wr * 64 + m * 16 + (lane >> 4) * 4 + r;
          float v = acc1[m][n][r] + bv;
          v = v > 0.f ? v : 0.f;
          *(ushort*)(LH + R * 512 + (C2 ^ ((R & 7) << 4))) = f2bf(v);
        }
    }
  };
  auto stage2 = [&](int c) {
#pragma unroll 1
    for (int k2 = 0; k2 < 4; ++k2) {
      short8 af[4][2];
#pragma unroll
      for (int m = 0; m < 4; ++m) {
        int row = wr * 64 + m * 16 + rA;
        af[m][0] = *(const short8*)(LH + row * 512 + ((k2 * 128 + klo) ^ xs));
        af[m][1] =
            *(const short8*)(LH + row * 512 + ((k2 * 128 + 64 + klo) ^ xs));
      }
#pragma unroll
      for (int j = 0; j < 8; ++j) {   // single-n: bg liveness = 8
        int row2 = wc * 128 + j * 16 + rA;
        const char* p = (const char*)w2m + (size_t)row2 * 2048 + c * 512 +
                        k2 * 128 + klo;
        short8 bg0 = *(const short8*)(p);
        short8 bg1 = *(const short8*)(p + 64);
        __builtin_amdgcn_s_setprio(1);
#pragma unroll
        for (int m = 0; m < 4; ++m) {
          acc2[m][j] = MFMA(af[m][0], bg0, acc2[m][j]);
          acc2[m][j] = MFMA(af[m][1], bg1, acc2[m][j]);
        }
        __builtin_amdgcn_s_setprio(0);
      }
    }
  };

  // ---------------- chunk 0: stage1 with in-register convert ----------------
  {
    f32x4 acc1[4][4] = {};
    ldx(0);
    stgB1(0, 0, 0);
    cvt(LA, 0);
    __syncthreads();
#pragma unroll 1
    for (int kt = 0; kt < 13; ++kt) {
      const int cur = kt & 1;
      if (kt < 12) { stgB1(0, kt + 1, cur ^ 1); ldx(kt + 1); }
      s1body(acc1, cur);
      if (kt < 12) cvt(LA + (cur ^ 1) * 16384, kt + 1);
      __syncthreads();
    }
    handoff(acc1, 0);
    __syncthreads();
#pragma unroll
    for (int m = 0; m < 4; ++m)
#pragma unroll
      for (int j = 0; j < 8; ++j) acc2[m][j] = (f32x4){0.f, 0.f, 0.f, 0.f};
    stage2(0);
  }
  // ---------------- chunks 1..3: stage1 via glds16 from xb ----------------
#pragma unroll 1
  for (int c = 1; c < 4; ++c) {
    f32x4 acc1[4][4] = {};
    stgA(0, 0);
    stgB1(c, 0, 0);
    __syncthreads();
#pragma unroll 1
    for (int kt = 0; kt < 13; ++kt) {
      const int cur = kt & 1;
      if (kt < 12) { stgA(kt + 1, cur ^ 1); stgB1(c, kt + 1, cur ^ 1); }
      s1body(acc1, cur);
      __syncthreads();
    }
    handoff(acc1, c);
    __syncthreads();
    stage2(c);
  }
  // ---------------- out epilogue ----------------
#pragma unroll
  for (int j = 0; j < 8; ++j) {
    int col = wc * 128 + j * 16 + rA;
    float bv = bias2[col];
#pragma unroll
    for (int m = 0; m < 4; ++m)
#pragma unroll
      for (int r = 0; r < 4; ++r) {
        int row = brow + wr * 64 + m * 16 + (lane >> 4) * 4 + r;
        float v = acc2[m][j][r] + bv;
        out[(size_t)row * OUT_C + col] = v > 0.f ? v : 0.f;
      }
  }
}

// ---------------- fallback pipeline (round-1 proven), used if ws too small ----------------
__global__ __launch_bounds__(256, 2) void gemm1_fused(
    const float* __restrict__ x, const ushort* __restrict__ w1p,
    const float* __restrict__ bias1, ushort* __restrict__ h1) {
  __shared__ ushort As[128 * 32];
  __shared__ ushort Bs[128 * 32];
  const int tid = threadIdx.x;
  const int lane = tid & 63, wid = tid >> 6;
  const int wr = wid >> 1, wc = wid & 1;
  const int brow = blockIdx.x * 128;
  const int bcol = blockIdx.y * 128;
  f32x4 acc[4][4] = {};
  const int arow = tid >> 1;
  const int acol0 = (tid & 1) * 16;
  const float* xrow = x + (size_t)(brow + arow) * IN_CH;
  for (int kt = 0; kt < 26; ++kt) {
    const int k0 = kt * 32;
#pragma unroll
    for (int c = 0; c < 2; ++c) {
      int idx16 = (wid * 2 + c) * 64 + lane;
      int row = idx16 >> 2, chunk = idx16 & 3;
      glds16(w1p + (size_t)(bcol + row) * KPAD + k0 + chunk * 8,
             (char*)Bs + (wid * 2 + c) * 1024);
    }
    union { ushort u[16]; uint4 q[2]; } pk;
    if (kt < 24) {
      const float* p = xrow + k0 + acol0;
#pragma unroll
      for (int j = 0; j < 8; ++j) {
        float2 v = *(const float2*)(p + j * 2);
        pk.u[j * 2] = f2bf(v.x);
        pk.u[j * 2 + 1] = f2bf(v.y);
      }
    } else {
#pragma unroll
      for (int j = 0; j < 16; ++j) {
        int col = k0 + acol0 + j;
        pk.u[j] = f2bf(col < IN_CH ? xrow[col] : 0.f);
      }
    }
    *(uint4*)&As[arow * 32 + acol0] = pk.q[0];
    *(uint4*)&As[arow * 32 + acol0 + 8] = pk.q[1];
    __syncthreads();
    const int kb = (lane >> 4) * 8, rA = lane & 15;
    short8 af[4], bfrag[4];
#pragma unroll
    for (int m = 0; m < 4; ++m)
      af[m] = *(const short8*)&As[(wr * 64 + m * 16 + rA) * 32 + kb];
#pragma unroll
    for (int n = 0; n < 4; ++n)
      bfrag[n] = *(const short8*)&Bs[(wc * 64 + n * 16 + rA) * 32 + kb];
#pragma unroll
    for (int m = 0; m < 4; ++m)
#pragma unroll
      for (int n = 0; n < 4; ++n)
        acc[m][n] = MFMA(af[m], bfrag[n], acc[m][n]);
    __syncthreads();
  }
  const int orow0 = brow + wr * 64;
  const int ocol0 = bcol + wc * 64;
#pragma unroll
  for (int n = 0; n < 4; ++n) {
    int col = ocol0 + n * 16 + (lane & 15);
    float bv = bias1[col];
#pragma unroll
    for (int m = 0; m < 4; ++m)
#pragma unroll
      for (int r = 0; r < 4; ++r) {
        int row = orow0 + m * 16 + (lane >> 4) * 4 + r;
        float v = acc[m][n][r] + bv;
        v = v > 0.f ? v : 0.f;
        h1[(size_t)row * Z1C + col] = f2bf(v);
      }
  }
}

__global__ __launch_bounds__(512, 2) void gemm2_fb(
    const ushort* __restrict__ h1, const ushort* __restrict__ w2m,
    const float* __restrict__ bias2, float* __restrict__ out) {
  __shared__ ushort As[128 * 32];
  __shared__ ushort Bs[512 * 32];
  const int tid = threadIdx.x;
  const int lane = tid & 63, wid = tid >> 6;
  const int wr = wid >> 2, wc = wid & 3;
  const int brow = blockIdx.x * 128;
  f32x4 acc[4][8] = {};
  for (int kt = 0; kt < 32; ++kt) {
    const int k0 = kt * 32;
    {
      int idx16 = wid * 64 + lane;
      int row = idx16 >> 2, chunk = idx16 & 3;
      glds16(h1 + (size_t)(brow + row) * Z1C + k0 + chunk * 8,
             (char*)As + wid * 1024);
    }
#pragma unroll
    for (int c = 0; c < 4; ++c) {
      int idx16 = c * 512 + wid * 64 + lane;
      int row = idx16 >> 2, chunk = idx16 & 3;
      glds16(w2m + (size_t)row * Z1C + k0 + chunk * 8,
             (char*)Bs + c * 8192 + wid * 1024);
    }
    __syncthreads();
    const int kb = (lane >> 4) * 8, rA = lane & 15;
    short8 af[4], bfrag[8];
#pragma unroll
    for (int m = 0; m < 4; ++m)
      af[m] = *(const short8*)&As[(wr * 64 + m * 16 + rA) * 32 + kb];
#pragma unroll
    for (int n = 0; n < 8; ++n)
      bfrag[n] = *(const short8*)&Bs[(wc * 128 + n * 16 + rA) * 32 + kb];
#pragma unroll
    for (int m = 0; m < 4; ++m)
#pragma unroll
      for (int n = 0; n < 8; ++n)
        acc[m][n] = MFMA(af[m], bfrag[n], acc[m][n]);
    __syncthreads();
  }
#pragma unroll
  for (int n = 0; n < 8; ++n) {
    int col = wc * 128 + n * 16 + (lane & 15);
    float bv = bias2[col];
#pragma unroll
    for (int m = 0; m < 4; ++m)
#pragma unroll
      for (int r = 0; r < 4; ++r) {
        int row = brow + wr * 64 + m * 16 + (lane >> 4) * 4 + r;
        float v = acc[m][n][r] + bv;
        out[(size_t)row * OUT_C + col] = v > 0.f ? v : 0.f;
      }
  }
}

extern "C" void kernel_launch(void* const* d_in, const int* in_sizes, int n_in,
                              void* d_out, int out_size, void* d_ws, size_t ws_size,
                              hipStream_t stream) {
  (void)in_sizes; (void)n_in; (void)out_size;
  const float* x   = (const float*)d_in[0];
  const float* W1  = (const float*)d_in[1];
  const float* b1  = (const float*)d_in[2];
  const float* Wc1 = (const float*)d_in[3];
  const float* bc1 = (const float*)d_in[4];
  const float* W2  = (const float*)d_in[5];
  const float* b2  = (const float*)d_in[6];
  const float* Wc2 = (const float*)d_in[7];
  const float* bc2 = (const float*)d_in[8];
  const float* MW0 = (const float*)d_in[9];
  const float* MW1 = (const float*)d_in[10];

  char* ws = (char*)d_ws;
  ushort* w1p   = (ushort*)ws;                   // 1024*832*2 = 1,703,936
  ushort* w2m   = (ushort*)(ws + 1703936);       //  512*1024*2 = 1,048,576
  float*  bias1 = (float*)(ws + 2752512);        // 4096
  float*  bias2 = (float*)(ws + 2756608);        // 2048
  ushort* xb    = (ushort*)(ws + 2758656);       // 32768*832*2 = 54,525,952
  const size_t WS_NEED = 2758656ull + 54525952ull;

  float* out = (float*)d_out;

  prep1<<<1024, 256, 0, stream>>>(W1, b1, Wc1, bc1, MW0, w1p, bias1);
  prep2<<<512, 256, 0, stream>>>(W2, b2, Wc2, bc2, MW1, w2m, bias2);

  if (ws_size >= WS_NEED) {
    fused<<<256, 512, 0, stream>>>(x, w1p, w2m, bias1, bias2, xb, out);
  } else {
    ushort* h1 = (ushort*)d_out;  // 32768x1024 bf16 aliases 32768x512 f32
    gemm1_fused<<<dim3(256, 8), 256, 0, stream>>>(x, w1p, bias1, h1);
    gemm2_fb<<<256, 512, 0, stream>>>(h1, w2m, bias2, out);
  }
}